// Round 8
// baseline (641.181 us; speedup 1.0000x reference)
//
#include <hip/hip_runtime.h>
#include <hip/hip_bf16.h>

#define D 256
#define BM 64
#define BN 512      // codes per tile (8 wave-cols x 64)
#define NT 16       // 8192 / BN
#define CAP 64
#define MARGIN 1.2e-3f

typedef short bf16x8 __attribute__((ext_vector_type(8)));
typedef float f32x4 __attribute__((ext_vector_type(4)));

__device__ inline unsigned short f2bf(float f) {
    __hip_bfloat16 h = __float2bfloat16(f);
    return *reinterpret_cast<unsigned short*>(&h);
}

// -------- kernel 0: fp32 -> bf16 convert (vectorized) --------
__global__ __launch_bounds__(256) void vq_tobf16(const float* __restrict__ in,
                                                 unsigned short* __restrict__ out, int n4) {
    int i = blockIdx.x * 256 + threadIdx.x;
    if (i >= n4) return;
    float4 v = ((const float4*)in)[i];
    ushort4 o;
    o.x = f2bf(v.x); o.y = f2bf(v.y); o.z = f2bf(v.z); o.w = f2bf(v.w);
    ((ushort4*)out)[i] = o;
}

// -------- kernel 1: sequential fp32 row sum-of-squares (XLA elemental order) ----
__global__ __launch_bounds__(256) void vq_rownorm(const float* __restrict__ x,
                                                  float* __restrict__ out,
                                                  int rows, float* loss_zero) {
#pragma clang fp contract(off)
    int r = blockIdx.x * blockDim.x + threadIdx.x;
    if (r == 0 && loss_zero) loss_zero[0] = 0.f;
    if (r >= rows) return;
    const float* p = x + (size_t)r * D;
    float s = 0.f;
    for (int d = 0; d < D; ++d) {
        float v = p[d];
        float pr = v * v;
        s = s + pr;
    }
    out[r] = s;
}

// -------- kernel 2: single-pass MFMA filter, 16 waves (2x8), R5-style loop ----
__global__ __launch_bounds__(1024, 4) void vq_argmin_mfma(
    const float* __restrict__ z, const float* __restrict__ emb,
    const unsigned short* __restrict__ zb, const unsigned short* __restrict__ eb,
    const float* __restrict__ znorm, const float* __restrict__ enorm,
    float* __restrict__ idxf, int K) {
#pragma clang fp contract(off)
    __shared__ unsigned short zsh[BM][264];   // 33,792 B
    __shared__ unsigned rowmin[BM];
    __shared__ int cnt[BM];
    __shared__ int candT[CAP][BM];            // 16,384 B (slot-major)
    __shared__ unsigned sbits[BM];
    __shared__ int sidx[BM];
    __shared__ int ovList[16];
    __shared__ int ovCnt;

    const int tid = threadIdx.x;
    const int w = tid >> 6;        // wave 0..15
    const int wr = w >> 3;         // wave-row 0..1 (32 rows each)
    const int wc = w & 7;          // wave-col 0..7 (64 codes each)
    const int l = tid & 63;
    const int q = l >> 4;          // 0..3
    const int lm = l & 15;
    const int rowBase = blockIdx.x * BM;

    if (tid < BM) {
        rowmin[tid] = 0x7f800000u; cnt[tid] = 0;
        sbits[tid] = 0xffffffffu;  sidx[tid] = 0x7fffffff;
    }
    if (tid == 0) ovCnt = 0;

    // stage z tile (bf16) into padded LDS (verified mapping; 2 rounds @1024 thr)
    #pragma unroll
    for (int rc = 0; rc < 2; ++rc) {
        int idx8 = tid + rc * 1024;
        int row = idx8 >> 5, c8 = idx8 & 31;
        uint4 v = *(const uint4*)(zb + (((size_t)(rowBase + row)) << 8) + c8 * 8);
        *(uint4*)&zsh[row][c8 * 8] = v;
    }

    // this wave's rows: rowBase + wr*32 + fr*16 + q*4 + e   (fr in 0..1)
    f32x4 nz4[2];
    #pragma unroll
    for (int fr = 0; fr < 2; ++fr)
        nz4[fr] = *(const f32x4*)&znorm[rowBase + wr * 32 + fr * 16 + q * 4];

    __syncthreads();   // zsh + init visible

    for (int tile = 0; tile < NT; ++tile) {
        const int codeBase = tile * BN + wc * 64;
        const unsigned short* ebw = eb + ((size_t)codeBase << 8);
        float ne[4];
        #pragma unroll
        for (int fc = 0; fc < 4; ++fc) ne[fc] = enorm[codeBase + fc * 16 + lm];

        f32x4 acc[2][4];
        #pragma unroll
        for (int a = 0; a < 2; ++a)
            #pragma unroll
            for (int b = 0; b < 4; ++b) acc[a][b] = (f32x4)0.f;

        #pragma unroll
        for (int kc = 0; kc < 8; ++kc) {
            bf16x8 af[2], bfr[4];
            #pragma unroll
            for (int fr = 0; fr < 2; ++fr)
                af[fr] = *(const bf16x8*)&zsh[wr * 32 + fr * 16 + lm][kc * 32 + q * 8];
            #pragma unroll
            for (int fc = 0; fc < 4; ++fc)
                bfr[fc] = *(const bf16x8*)(ebw + (((size_t)(fc * 16 + lm)) << 8) + kc * 32 + q * 8);
            #pragma unroll
            for (int fr = 0; fr < 2; ++fr)
                #pragma unroll
                for (int fc = 0; fc < 4; ++fc)
                    acc[fr][fc] = __builtin_amdgcn_mfma_f32_16x16x32_bf16(af[fr], bfr[fc], acc[fr][fc], 0, 0, 0);
        }

        // ---- tile epilogue (no barriers): reg-min -> atomicMin -> collect ----
        f32x4 m4[2];
        #pragma unroll
        for (int fr = 0; fr < 2; ++fr) {
            #pragma unroll
            for (int e = 0; e < 4; ++e) {
                float m = 3.4e38f;
                #pragma unroll
                for (int fc = 0; fc < 4; ++fc) {
                    float s = (nz4[fr][e] + ne[fc]) - 2.0f * acc[fr][fc][e];
                    m = fminf(m, s);
                }
                m4[fr][e] = m;
                #pragma unroll
                for (int off = 1; off < 16; off <<= 1)
                    m = fminf(m, __shfl_xor(m, off));
                if (lm == 0)
                    atomicMin(&rowmin[wr * 32 + fr * 16 + q * 4 + e], __float_as_uint(m));
            }
        }
        // threshold read (stale rowmin >= finalMin, so capture guarantee holds)
        #pragma unroll
        for (int fr = 0; fr < 2; ++fr) {
            uint4 u = *(const uint4*)&rowmin[wr * 32 + fr * 16 + q * 4];
            f32x4 thr = {__uint_as_float(u.x) + MARGIN, __uint_as_float(u.y) + MARGIN,
                         __uint_as_float(u.z) + MARGIN, __uint_as_float(u.w) + MARGIN};
            #pragma unroll
            for (int e = 0; e < 4; ++e) {
                if (m4[fr][e] >= thr[e]) continue;   // fast skip
                int row = wr * 32 + fr * 16 + q * 4 + e;
                #pragma unroll
                for (int fc = 0; fc < 4; ++fc) {
                    float s = (nz4[fr][e] + ne[fc]) - 2.0f * acc[fr][fc][e];
                    if (s < thr[e]) {
                        int slot = atomicAdd(&cnt[row], 1);
                        if (slot < CAP) candT[slot][row] = codeBase + fc * 16 + lm;
                    }
                }
            }
        }
    }
    __syncthreads();

    // ================= exact rescore (bit-exact R2 semantics, unchanged) ========
    const int r = tid & 63;        // one row per lane
    const int c0 = tid >> 6;       // candidate slot, stride 16
    const int grow = rowBase + r;
    const float Anz = znorm[grow];
    const float4* zp4 = (const float4*)(z + ((size_t)grow << 8));

    float bestS = 3.4e38f; int bestK = 0x7fffffff;
    {
        const int n = min(cnt[r], CAP);
        for (int c = c0; c < n; c += 16) {
            int k = candT[c][r];
            const float4* ep4 = (const float4*)(emb + ((size_t)k << 8));
            float s = 0.f;
            #pragma unroll 8
            for (int d4 = 0; d4 < 64; ++d4) {
                float4 a = zp4[d4], b = ep4[d4];
                s = s + a.x * b.x;   // strict mul-then-add, ascending d
                s = s + a.y * b.y;
                s = s + a.z * b.z;
                s = s + a.w * b.w;
            }
            float sc = (Anz + enorm[k]) - 2.0f * s;
            if (sc < bestS || (sc == bestS && k < bestK)) { bestS = sc; bestK = k; }
        }
    }
    if (bestK != 0x7fffffff) atomicMin(&sbits[r], __float_as_uint(bestS));
    if (tid < BM && cnt[tid] > CAP) {          // overflow rows (should be never)
        int o = atomicAdd(&ovCnt, 1);
        if (o < 16) ovList[o] = tid;
    }
    __syncthreads();

    // rare cooperative fallback: full exact scan for overflow rows
    const int nov = min(ovCnt, 16);
    for (int o = 0; o < nov; ++o) {
        const int rr = ovList[o];
        const float Az = znorm[rowBase + rr];
        const float4* zr4 = (const float4*)(z + ((size_t)(rowBase + rr) << 8));
        float bS = 3.4e38f; int bK = 0x7fffffff;
        for (int k = tid; k < K; k += 1024) {
            const float4* ep4 = (const float4*)(emb + ((size_t)k << 8));
            float s = 0.f;
            #pragma unroll 8
            for (int d4 = 0; d4 < 64; ++d4) {
                float4 a = zr4[d4], b = ep4[d4];
                s = s + a.x * b.x; s = s + a.y * b.y;
                s = s + a.z * b.z; s = s + a.w * b.w;
            }
            float sc = (Az + enorm[k]) - 2.0f * s;
            if (sc < bS || (sc == bS && k < bK)) { bS = sc; bK = k; }
        }
        atomicMin(&sbits[rr], __float_as_uint(bS));
        __syncthreads();
        if (__float_as_uint(bS) == sbits[rr]) atomicMin(&sidx[rr], bK);
        __syncthreads();
    }

    // stage 2: first-index tie-break among exact-score minima
    if (bestK != 0x7fffffff && __float_as_uint(bestS) == sbits[r])
        atomicMin(&sidx[r], bestK);
    __syncthreads();
    if (tid < BM) idxf[rowBase + tid] = (float)sidx[tid];
}

// -------- kernel 3: gather z_q + loss accumulation --------
__global__ __launch_bounds__(256) void vq_gather(
    const float* __restrict__ z, const float* __restrict__ emb,
    const float* __restrict__ idxf, float* __restrict__ zq,
    float* __restrict__ loss, float scale) {
    const int tid = threadIdx.x;
    const int lane = tid & 63, w = tid >> 6;
    const int rowBase = blockIdx.x * 64;
    float lsum = 0.f;
    for (int t = 0; t < 16; ++t) {
        int gr = rowBase + w * 16 + t;
        int k = (int)idxf[gr];
        float4 e  = ((const float4*)emb)[(size_t)k * 64 + lane];
        float4 zv = ((const float4*)z)[(size_t)gr * 64 + lane];
        ((float4*)zq)[(size_t)gr * 64 + lane] = e;
        float dx = e.x - zv.x, dy = e.y - zv.y, dz = e.z - zv.z, dw = e.w - zv.w;
        lsum = fmaf(dx, dx, lsum); lsum = fmaf(dy, dy, lsum);
        lsum = fmaf(dz, dz, lsum); lsum = fmaf(dw, dw, lsum);
    }
    #pragma unroll
    for (int off = 32; off; off >>= 1) lsum += __shfl_down(lsum, off);
    __shared__ float ps[4];
    if (lane == 0) ps[w] = lsum;
    __syncthreads();
    if (tid == 0) atomicAdd(loss, (ps[0] + ps[1] + ps[2] + ps[3]) * scale);
}

extern "C" void kernel_launch(void* const* d_in, const int* in_sizes, int n_in,
                              void* d_out, int out_size, void* d_ws, size_t ws_size,
                              hipStream_t stream) {
    const float* z   = (const float*)d_in[0];
    const float* emb = (const float*)d_in[1];
    const int N = in_sizes[0] / D;   // 16384
    const int K = in_sizes[1] / D;   // 8192

    float* out  = (float*)d_out;
    float* zq   = out;
    const size_t Z = (size_t)N * D;  // 4,194,304 floats
    float* loss = out + Z;
    float* idxf = loss + 1;

    // scratch in the zq tail region (overwritten by gather at the end):
    char* base = (char*)zq;
    unsigned short* eb = (unsigned short*)base;                          // 4 MB
    unsigned short* zb = (unsigned short*)(base + (size_t)K * D * 2);    // 8 MB
    float* znorm = (float*)(base + (size_t)K * D * 2 + (size_t)N * D * 2);
    float* enorm = znorm + N;

    const int n4z = (N * D) / 4, n4e = (K * D) / 4;
    vq_tobf16 <<<(n4z + 255) / 256, 256, 0, stream>>>(z, zb, n4z);
    vq_tobf16 <<<(n4e + 255) / 256, 256, 0, stream>>>(emb, eb, n4e);
    vq_rownorm<<<(N + 255) / 256, 256, 0, stream>>>(z, znorm, N, loss);
    vq_rownorm<<<(K + 255) / 256, 256, 0, stream>>>(emb, enorm, K, loss);
    vq_argmin_mfma<<<N / BM, 1024, 0, stream>>>(z, emb, zb, eb, znorm, enorm, idxf, K);
    vq_gather <<<N / 64, 256, 0, stream>>>(z, emb, idxf, zq, loss,
                                           1.25f / ((float)N * (float)D));
}

// Round 9
// 294.516 us; speedup vs baseline: 2.1771x; 2.1771x over previous
//
#include <hip/hip_runtime.h>
#include <hip/hip_bf16.h>

#define D 256
#define BM 64
#define BN 512      // codes per tile (8 waves x 64)
#define NT 16       // 8192 / BN
#define CAP 64
#define MARGIN 1.2e-3f

typedef short bf16x8 __attribute__((ext_vector_type(8)));
typedef float f32x4 __attribute__((ext_vector_type(4)));

__device__ inline unsigned short f2bf(float f) {
    __hip_bfloat16 h = __float2bfloat16(f);
    return *reinterpret_cast<unsigned short*>(&h);
}

// -------- kernel 0a: fp32 -> bf16 convert (row-major, for z) --------
__global__ __launch_bounds__(256) void vq_tobf16(const float* __restrict__ in,
                                                 unsigned short* __restrict__ out, int n4) {
    int i = blockIdx.x * 256 + threadIdx.x;
    if (i >= n4) return;
    float4 v = ((const float4*)in)[i];
    ushort4 o;
    o.x = f2bf(v.x); o.y = f2bf(v.y); o.z = f2bf(v.z); o.w = f2bf(v.w);
    ((ushort4*)out)[i] = o;
}

// -------- kernel 0b: fp32 emb -> bf16 in MFMA-fragment order --------
// fragment f(cb,kc,fc) holds lane l=q*16+lm's bf16x8 at ((cb*8+kc)*4+fc)*512 + l*8
// semantics: lane l <- emb[cb*64 + fc*16 + lm][kc*32 + q*8 .. +7] (bf16 RNE)
__global__ __launch_bounds__(512) void vq_ebfrag(const float* __restrict__ emb,
                                                 unsigned short* __restrict__ ebf) {
    const int cb = blockIdx.x;          // 0..127
    const int tid = threadIdx.x;
    const int kc = tid >> 6;            // wave index == kc 0..7
    const int l = tid & 63;
    const int q = l >> 4, lm = l & 15;
    const float4* emb4 = (const float4*)emb;
    #pragma unroll
    for (int fc = 0; fc < 4; ++fc) {
        const int code = cb * 64 + fc * 16 + lm;
        float4 a = emb4[(size_t)code * 64 + kc * 8 + q * 2];
        float4 b = emb4[(size_t)code * 64 + kc * 8 + q * 2 + 1];
        ushort4 o0, o1;
        o0.x = f2bf(a.x); o0.y = f2bf(a.y); o0.z = f2bf(a.z); o0.w = f2bf(a.w);
        o1.x = f2bf(b.x); o1.y = f2bf(b.y); o1.z = f2bf(b.z); o1.w = f2bf(b.w);
        unsigned short* dst = ebf + (((size_t)(cb * 8 + kc) * 4 + fc) << 9) + l * 8;
        *(ushort4*)dst = o0;
        *(ushort4*)(dst + 4) = o1;
    }
}

// -------- kernel 1: sequential fp32 row sum-of-squares (XLA elemental order) ----
__global__ __launch_bounds__(256) void vq_rownorm(const float* __restrict__ x,
                                                  float* __restrict__ out,
                                                  int rows, float* loss_zero) {
#pragma clang fp contract(off)
    int r = blockIdx.x * blockDim.x + threadIdx.x;
    if (r == 0 && loss_zero) loss_zero[0] = 0.f;
    if (r >= rows) return;
    const float* p = x + (size_t)r * D;
    float s = 0.f;
    for (int d = 0; d < D; ++d) {
        float v = p[d];
        float pr = v * v;
        s = s + pr;
    }
    out[r] = s;
}

// -------- kernel 2: two-pass MFMA filter (coalesced fragment B) + exact rescore
__global__ __launch_bounds__(512, 2) void vq_argmin_mfma(
    const float* __restrict__ z, const float* __restrict__ emb,
    const unsigned short* __restrict__ zb, const unsigned short* __restrict__ ebf,
    const float* __restrict__ znorm, const float* __restrict__ enorm,
    float* __restrict__ idxf, int K) {
#pragma clang fp contract(off)
    __shared__ unsigned short zsh[BM][264];   // 33,792 B
    __shared__ unsigned rowmin[BM];
    __shared__ int cnt[BM];
    __shared__ int candT[CAP][BM];            // 16,384 B (slot-major)
    __shared__ unsigned sbits[BM];
    __shared__ int sidx[BM];
    __shared__ int ovList[16];
    __shared__ int ovCnt;

    const int tid = threadIdx.x;
    const int w = tid >> 6;        // wave 0..7
    const int l = tid & 63;
    const int q = l >> 4;          // 0..3
    const int lm = l & 15;
    const int rowBase = blockIdx.x * BM;

    if (tid < BM) {
        rowmin[tid] = 0x7f800000u; cnt[tid] = 0;
        sbits[tid] = 0xffffffffu;  sidx[tid] = 0x7fffffff;
    }
    if (tid == 0) ovCnt = 0;

    // stage z tile (bf16) into padded LDS (R4/R5-verified mapping)
    #pragma unroll
    for (int rc = 0; rc < 4; ++rc) {
        int idx8 = tid + rc * 512;
        int row = idx8 >> 5, c8 = idx8 & 31;
        uint4 v = *(const uint4*)(zb + (((size_t)(rowBase + row)) << 8) + c8 * 8);
        *(uint4*)&zsh[row][c8 * 8] = v;
    }

    f32x4 nz4[4];
    #pragma unroll
    for (int fr = 0; fr < 4; ++fr)
        nz4[fr] = *(const f32x4*)&znorm[rowBase + fr * 16 + q * 4];

    __syncthreads();

    // ================= pass 1: per-row approx min (registers only) ===============
    f32x4 m4[4];
    #pragma unroll
    for (int fr = 0; fr < 4; ++fr) m4[fr] = (f32x4)3.4e38f;

    for (int tile = 0; tile < NT; ++tile) {
        const int cb = tile * 8 + w;                 // this wave's 64-code block
        const int codeBase = cb * 64;
        const unsigned short* fb = ebf + (((size_t)cb * 8) << 11);  // cb*8 frags * 2048
        float ne[4];
        #pragma unroll
        for (int fc = 0; fc < 4; ++fc) ne[fc] = enorm[codeBase + fc * 16 + lm];

        f32x4 acc[4][4];
        #pragma unroll
        for (int a = 0; a < 4; ++a)
            #pragma unroll
            for (int b = 0; b < 4; ++b) acc[a][b] = (f32x4)0.f;

        #pragma unroll
        for (int kc = 0; kc < 8; ++kc) {
            bf16x8 af[4], bfr[4];
            #pragma unroll
            for (int fr = 0; fr < 4; ++fr)
                af[fr] = *(const bf16x8*)&zsh[fr * 16 + lm][kc * 32 + q * 8];
            #pragma unroll
            for (int fc = 0; fc < 4; ++fc)   // contiguous 1 KB per wave-load
                bfr[fc] = *(const bf16x8*)(fb + kc * 2048 + fc * 512 + l * 8);
            #pragma unroll
            for (int fr = 0; fr < 4; ++fr)
                #pragma unroll
                for (int fc = 0; fc < 4; ++fc)
                    acc[fr][fc] = __builtin_amdgcn_mfma_f32_16x16x32_bf16(af[fr], bfr[fc], acc[fr][fc], 0, 0, 0);
        }

        #pragma unroll
        for (int fr = 0; fr < 4; ++fr)
            #pragma unroll
            for (int fc = 0; fc < 4; ++fc) {
                #pragma unroll
                for (int e = 0; e < 4; ++e) {
                    float s = (nz4[fr][e] + ne[fc]) - 2.0f * acc[fr][fc][e];
                    m4[fr][e] = fminf(m4[fr][e], s);
                }
            }
    }

    #pragma unroll
    for (int fr = 0; fr < 4; ++fr) {
        #pragma unroll
        for (int e = 0; e < 4; ++e) {
            float m = m4[fr][e];
            #pragma unroll
            for (int off = 1; off < 16; off <<= 1)
                m = fminf(m, __shfl_xor(m, off));
            if (lm == 0)
                atomicMin(&rowmin[fr * 16 + q * 4 + e], __float_as_uint(m));
        }
    }
    __syncthreads();

    // ================= pass 2: collect candidates vs final threshold ============
    f32x4 thr4[4];
    #pragma unroll
    for (int fr = 0; fr < 4; ++fr) {
        uint4 u = *(const uint4*)&rowmin[fr * 16 + q * 4];
        thr4[fr][0] = __uint_as_float(u.x) + MARGIN;
        thr4[fr][1] = __uint_as_float(u.y) + MARGIN;
        thr4[fr][2] = __uint_as_float(u.z) + MARGIN;
        thr4[fr][3] = __uint_as_float(u.w) + MARGIN;
    }

    for (int tile = 0; tile < NT; ++tile) {
        const int cb = tile * 8 + w;
        const int codeBase = cb * 64;
        const unsigned short* fb = ebf + (((size_t)cb * 8) << 11);
        float ne[4];
        #pragma unroll
        for (int fc = 0; fc < 4; ++fc) ne[fc] = enorm[codeBase + fc * 16 + lm];

        f32x4 acc[4][4];
        #pragma unroll
        for (int a = 0; a < 4; ++a)
            #pragma unroll
            for (int b = 0; b < 4; ++b) acc[a][b] = (f32x4)0.f;

        #pragma unroll
        for (int kc = 0; kc < 8; ++kc) {
            bf16x8 af[4], bfr[4];
            #pragma unroll
            for (int fr = 0; fr < 4; ++fr)
                af[fr] = *(const bf16x8*)&zsh[fr * 16 + lm][kc * 32 + q * 8];
            #pragma unroll
            for (int fc = 0; fc < 4; ++fc)
                bfr[fc] = *(const bf16x8*)(fb + kc * 2048 + fc * 512 + l * 8);
            #pragma unroll
            for (int fr = 0; fr < 4; ++fr)
                #pragma unroll
                for (int fc = 0; fc < 4; ++fc)
                    acc[fr][fc] = __builtin_amdgcn_mfma_f32_16x16x32_bf16(af[fr], bfr[fc], acc[fr][fc], 0, 0, 0);
        }

        #pragma unroll
        for (int fr = 0; fr < 4; ++fr)
            #pragma unroll
            for (int fc = 0; fc < 4; ++fc) {
                #pragma unroll
                for (int e = 0; e < 4; ++e) {
                    float s = (nz4[fr][e] + ne[fc]) - 2.0f * acc[fr][fc][e];
                    if (s < thr4[fr][e]) {
                        int row = fr * 16 + q * 4 + e;
                        int slot = atomicAdd(&cnt[row], 1);
                        if (slot < CAP) candT[slot][row] = codeBase + fc * 16 + lm;
                    }
                }
            }
    }
    __syncthreads();

    // ================= exact rescore (bit-exact R2 semantics, unchanged) ========
    const int r = tid & 63;        // one row per lane
    const int c0 = tid >> 6;       // candidate slot stride-8
    const int grow = rowBase + r;
    const float Anz = znorm[grow];
    const float4* zp4 = (const float4*)(z + ((size_t)grow << 8));

    float bestS = 3.4e38f; int bestK = 0x7fffffff;
    {
        const int n = min(cnt[r], CAP);
        for (int c = c0; c < n; c += 8) {
            int k = candT[c][r];
            const float4* ep4 = (const float4*)(emb + ((size_t)k << 8));
            float s = 0.f;
            #pragma unroll 8
            for (int d4 = 0; d4 < 64; ++d4) {
                float4 a = zp4[d4], b = ep4[d4];
                s = s + a.x * b.x;   // strict mul-then-add, ascending d
                s = s + a.y * b.y;
                s = s + a.z * b.z;
                s = s + a.w * b.w;
            }
            float sc = (Anz + enorm[k]) - 2.0f * s;
            if (sc < bestS || (sc == bestS && k < bestK)) { bestS = sc; bestK = k; }
        }
    }
    if (bestK != 0x7fffffff) atomicMin(&sbits[r], __float_as_uint(bestS));
    if (tid < BM && cnt[tid] > CAP) {          // overflow rows (should be never)
        int o = atomicAdd(&ovCnt, 1);
        if (o < 16) ovList[o] = tid;
    }
    __syncthreads();

    // rare cooperative fallback: full exact scan for overflow rows
    const int nov = min(ovCnt, 16);
    for (int o = 0; o < nov; ++o) {
        const int rr = ovList[o];
        const float Az = znorm[rowBase + rr];
        const float4* zr4 = (const float4*)(z + ((size_t)(rowBase + rr) << 8));
        float bS = 3.4e38f; int bK = 0x7fffffff;
        for (int k = tid; k < K; k += 512) {
            const float4* ep4 = (const float4*)(emb + ((size_t)k << 8));
            float s = 0.f;
            #pragma unroll 8
            for (int d4 = 0; d4 < 64; ++d4) {
                float4 a = zr4[d4], b = ep4[d4];
                s = s + a.x * b.x; s = s + a.y * b.y;
                s = s + a.z * b.z; s = s + a.w * b.w;
            }
            float sc = (Az + enorm[k]) - 2.0f * s;
            if (sc < bS || (sc == bS && k < bK)) { bS = sc; bK = k; }
        }
        atomicMin(&sbits[rr], __float_as_uint(bS));
        __syncthreads();
        if (__float_as_uint(bS) == sbits[rr]) atomicMin(&sidx[rr], bK);
        __syncthreads();
    }

    // stage 2: first-index tie-break among exact-score minima
    if (bestK != 0x7fffffff && __float_as_uint(bestS) == sbits[r])
        atomicMin(&sidx[r], bestK);
    __syncthreads();
    if (tid < BM) idxf[rowBase + tid] = (float)sidx[tid];
}

// -------- kernel 3: gather z_q + loss accumulation --------
__global__ __launch_bounds__(256) void vq_gather(
    const float* __restrict__ z, const float* __restrict__ emb,
    const float* __restrict__ idxf, float* __restrict__ zq,
    float* __restrict__ loss, float scale) {
    const int tid = threadIdx.x;
    const int lane = tid & 63, w = tid >> 6;
    const int rowBase = blockIdx.x * 64;
    float lsum = 0.f;
    for (int t = 0; t < 16; ++t) {
        int gr = rowBase + w * 16 + t;
        int k = (int)idxf[gr];
        float4 e  = ((const float4*)emb)[(size_t)k * 64 + lane];
        float4 zv = ((const float4*)z)[(size_t)gr * 64 + lane];
        ((float4*)zq)[(size_t)gr * 64 + lane] = e;
        float dx = e.x - zv.x, dy = e.y - zv.y, dz = e.z - zv.z, dw = e.w - zv.w;
        lsum = fmaf(dx, dx, lsum); lsum = fmaf(dy, dy, lsum);
        lsum = fmaf(dz, dz, lsum); lsum = fmaf(dw, dw, lsum);
    }
    #pragma unroll
    for (int off = 32; off; off >>= 1) lsum += __shfl_down(lsum, off);
    __shared__ float ps[4];
    if (lane == 0) ps[w] = lsum;
    __syncthreads();
    if (tid == 0) atomicAdd(loss, (ps[0] + ps[1] + ps[2] + ps[3]) * scale);
}

extern "C" void kernel_launch(void* const* d_in, const int* in_sizes, int n_in,
                              void* d_out, int out_size, void* d_ws, size_t ws_size,
                              hipStream_t stream) {
    const float* z   = (const float*)d_in[0];
    const float* emb = (const float*)d_in[1];
    const int N = in_sizes[0] / D;   // 16384
    const int K = in_sizes[1] / D;   // 8192

    float* out  = (float*)d_out;
    float* zq   = out;
    const size_t Z = (size_t)N * D;  // 4,194,304 floats
    float* loss = out + Z;
    float* idxf = loss + 1;

    // scratch in the zq tail region (overwritten by gather at the end):
    char* base = (char*)zq;
    unsigned short* ebf = (unsigned short*)base;                         // 4 MB
    unsigned short* zb  = (unsigned short*)(base + (size_t)K * D * 2);   // 8 MB
    float* znorm = (float*)(base + (size_t)K * D * 2 + (size_t)N * D * 2);
    float* enorm = znorm + N;

    const int n4z = (N * D) / 4;
    vq_tobf16 <<<(n4z + 255) / 256, 256, 0, stream>>>(z, zb, n4z);
    vq_ebfrag <<<K / 64, 512, 0, stream>>>(emb, ebf);
    vq_rownorm<<<(N + 255) / 256, 256, 0, stream>>>(z, znorm, N, loss);
    vq_rownorm<<<(K + 255) / 256, 256, 0, stream>>>(emb, enorm, K, loss);
    vq_argmin_mfma<<<N / BM, 512, 0, stream>>>(z, emb, zb, ebf, znorm, enorm, idxf, K);
    vq_gather <<<N / 64, 256, 0, stream>>>(z, emb, idxf, zq, loss,
                                           1.25f / ((float)N * (float)D));
}

// Round 10
// 256.833 us; speedup vs baseline: 2.4965x; 1.1467x over previous
//
#include <hip/hip_runtime.h>
#include <hip/hip_bf16.h>

#define D 256
#define BM 32
#define NT 16       // code tiles: 16 x (8 waves x 64 codes) = 8192
#define CAP 128
#define MARGIN 1.2e-3f

typedef short bf16x8 __attribute__((ext_vector_type(8)));
typedef float f32x4 __attribute__((ext_vector_type(4)));

__device__ inline unsigned short f2bf(float f) {
    __hip_bfloat16 h = __float2bfloat16(f);
    return *reinterpret_cast<unsigned short*>(&h);
}

// -------- kernel 0a: fp32 -> bf16 convert (row-major, for z) --------
__global__ __launch_bounds__(256) void vq_tobf16(const float* __restrict__ in,
                                                 unsigned short* __restrict__ out, int n4) {
    int i = blockIdx.x * 256 + threadIdx.x;
    if (i >= n4) return;
    float4 v = ((const float4*)in)[i];
    ushort4 o;
    o.x = f2bf(v.x); o.y = f2bf(v.y); o.z = f2bf(v.z); o.w = f2bf(v.w);
    ((ushort4*)out)[i] = o;
}

// -------- kernel 0b: fp32 emb -> bf16 in MFMA-fragment order (R9-verified) ----
// fragment f(cb,kc,fc): lane l <- emb[cb*64 + fc*16 + (l&15)][kc*32 + (l>>4)*8 ..+7]
__global__ __launch_bounds__(512) void vq_ebfrag(const float* __restrict__ emb,
                                                 unsigned short* __restrict__ ebf) {
    const int cb = blockIdx.x;          // 0..127
    const int tid = threadIdx.x;
    const int kc = tid >> 6;            // wave index == kc 0..7
    const int l = tid & 63;
    const int q = l >> 4, lm = l & 15;
    const float4* emb4 = (const float4*)emb;
    #pragma unroll
    for (int fc = 0; fc < 4; ++fc) {
        const int code = cb * 64 + fc * 16 + lm;
        float4 a = emb4[(size_t)code * 64 + kc * 8 + q * 2];
        float4 b = emb4[(size_t)code * 64 + kc * 8 + q * 2 + 1];
        ushort4 o0, o1;
        o0.x = f2bf(a.x); o0.y = f2bf(a.y); o0.z = f2bf(a.z); o0.w = f2bf(a.w);
        o1.x = f2bf(b.x); o1.y = f2bf(b.y); o1.z = f2bf(b.z); o1.w = f2bf(b.w);
        unsigned short* dst = ebf + (((size_t)(cb * 8 + kc) * 4 + fc) << 9) + l * 8;
        *(ushort4*)dst = o0;
        *(ushort4*)(dst + 4) = o1;
    }
}

// -------- kernel 1: sequential fp32 row sum-of-squares (XLA elemental order) ----
__global__ __launch_bounds__(256) void vq_rownorm(const float* __restrict__ x,
                                                  float* __restrict__ out,
                                                  int rows, float* loss_zero) {
#pragma clang fp contract(off)
    int r = blockIdx.x * blockDim.x + threadIdx.x;
    if (r == 0 && loss_zero) loss_zero[0] = 0.f;
    if (r >= rows) return;
    const float* p = x + (size_t)r * D;
    float s = 0.f;
    for (int d = 0; d < D; ++d) {
        float v = p[d];
        float pr = v * v;
        s = s + pr;
    }
    out[r] = s;
}

// -------- kernel 2: single-pass MFMA filter (BM=32, 2 blocks/CU) + rescore ----
__global__ __launch_bounds__(512, 4) void vq_argmin_mfma(
    const float* __restrict__ z, const float* __restrict__ emb,
    const unsigned short* __restrict__ zb, const unsigned short* __restrict__ ebf,
    const float* __restrict__ znorm, const float* __restrict__ enorm,
    float* __restrict__ idxf, int K) {
#pragma clang fp contract(off)
    __shared__ unsigned short zsh[BM][264];   // 16,896 B
    __shared__ unsigned rowmin[BM];
    __shared__ int cnt[BM];
    __shared__ int candT[CAP][BM];            // 16,384 B (slot-major)
    __shared__ unsigned sbits[BM];
    __shared__ int sidx[BM];
    __shared__ int ovList[16];
    __shared__ int ovCnt;

    const int tid = threadIdx.x;
    const int w = tid >> 6;        // wave 0..7 (code-column)
    const int l = tid & 63;
    const int q = l >> 4;          // 0..3
    const int lm = l & 15;
    const int rowBase = blockIdx.x * BM;

    if (tid < BM) {
        rowmin[tid] = 0x7f800000u; cnt[tid] = 0;
        sbits[tid] = 0xffffffffu;  sidx[tid] = 0x7fffffff;
    }
    if (tid == 0) ovCnt = 0;

    // stage z tile (bf16) into padded LDS: 32 rows x 32 octets = 2 rounds
    #pragma unroll
    for (int rc = 0; rc < 2; ++rc) {
        int idx8 = tid + rc * 512;
        int row = idx8 >> 5, c8 = idx8 & 31;
        uint4 v = *(const uint4*)(zb + (((size_t)(rowBase + row)) << 8) + c8 * 8);
        *(uint4*)&zsh[row][c8 * 8] = v;
    }

    f32x4 nz4[2];
    #pragma unroll
    for (int fr = 0; fr < 2; ++fr)
        nz4[fr] = *(const f32x4*)&znorm[rowBase + fr * 16 + q * 4];

    __syncthreads();

    for (int tile = 0; tile < NT; ++tile) {
        const int cb = tile * 8 + w;                 // this wave's 64-code block
        const int codeBase = cb * 64;
        const unsigned short* fb = ebf + (((size_t)cb * 8) << 11);
        float ne[4];
        #pragma unroll
        for (int fc = 0; fc < 4; ++fc) ne[fc] = enorm[codeBase + fc * 16 + lm];

        f32x4 acc[2][4];
        #pragma unroll
        for (int a = 0; a < 2; ++a)
            #pragma unroll
            for (int b = 0; b < 4; ++b) acc[a][b] = (f32x4)0.f;

        #pragma unroll
        for (int kc = 0; kc < 8; ++kc) {
            bf16x8 af[2], bfr[4];
            #pragma unroll
            for (int fr = 0; fr < 2; ++fr)
                af[fr] = *(const bf16x8*)&zsh[fr * 16 + lm][kc * 32 + q * 8];
            #pragma unroll
            for (int fc = 0; fc < 4; ++fc)   // contiguous 1 KB per wave-load
                bfr[fc] = *(const bf16x8*)(fb + kc * 2048 + fc * 512 + l * 8);
            #pragma unroll
            for (int fr = 0; fr < 2; ++fr)
                #pragma unroll
                for (int fc = 0; fc < 4; ++fc)
                    acc[fr][fc] = __builtin_amdgcn_mfma_f32_16x16x32_bf16(af[fr], bfr[fc], acc[fr][fc], 0, 0, 0);
        }

        // ---- tile epilogue (no barriers): reg-min -> atomicMin -> collect ----
        f32x4 m4[2];
        #pragma unroll
        for (int fr = 0; fr < 2; ++fr) {
            #pragma unroll
            for (int e = 0; e < 4; ++e) {
                float m = 3.4e38f;
                #pragma unroll
                for (int fc = 0; fc < 4; ++fc) {
                    float s = (nz4[fr][e] + ne[fc]) - 2.0f * acc[fr][fc][e];
                    m = fminf(m, s);
                }
                m4[fr][e] = m;
                #pragma unroll
                for (int off = 1; off < 16; off <<= 1)
                    m = fminf(m, __shfl_xor(m, off));
                if (lm == 0)
                    atomicMin(&rowmin[fr * 16 + q * 4 + e], __float_as_uint(m));
            }
        }
        // threshold read (running rowmin >= finalMin, so capture guarantee holds)
        #pragma unroll
        for (int fr = 0; fr < 2; ++fr) {
            uint4 u = *(const uint4*)&rowmin[fr * 16 + q * 4];
            f32x4 thr = {__uint_as_float(u.x) + MARGIN, __uint_as_float(u.y) + MARGIN,
                         __uint_as_float(u.z) + MARGIN, __uint_as_float(u.w) + MARGIN};
            #pragma unroll
            for (int e = 0; e < 4; ++e) {
                if (m4[fr][e] >= thr[e]) continue;   // fast skip
                int row = fr * 16 + q * 4 + e;
                #pragma unroll
                for (int fc = 0; fc < 4; ++fc) {
                    float s = (nz4[fr][e] + ne[fc]) - 2.0f * acc[fr][fc][e];
                    if (s < thr[e]) {
                        int slot = atomicAdd(&cnt[row], 1);
                        if (slot < CAP) candT[slot][row] = codeBase + fc * 16 + lm;
                    }
                }
            }
        }
    }
    __syncthreads();

    // ================= exact rescore (bit-exact R2 semantics) ===================
    const int r = tid & 31;        // one row per lane-half
    const int c0 = tid >> 5;       // candidate slot, stride 16
    const int grow = rowBase + r;
    const float Anz = znorm[grow];
    const float4* zp4 = (const float4*)(z + ((size_t)grow << 8));

    float bestS = 3.4e38f; int bestK = 0x7fffffff;
    {
        const int n = min(cnt[r], CAP);
        for (int c = c0; c < n; c += 16) {
            int k = candT[c][r];
            const float4* ep4 = (const float4*)(emb + ((size_t)k << 8));
            float s = 0.f;
            #pragma unroll 8
            for (int d4 = 0; d4 < 64; ++d4) {
                float4 a = zp4[d4], b = ep4[d4];
                s = s + a.x * b.x;   // strict mul-then-add, ascending d
                s = s + a.y * b.y;
                s = s + a.z * b.z;
                s = s + a.w * b.w;
            }
            float sc = (Anz + enorm[k]) - 2.0f * s;
            if (sc < bestS || (sc == bestS && k < bestK)) { bestS = sc; bestK = k; }
        }
    }
    if (bestK != 0x7fffffff) atomicMin(&sbits[r], __float_as_uint(bestS));
    if (tid < BM && cnt[tid] > CAP) {          // overflow rows (should be never)
        int o = atomicAdd(&ovCnt, 1);
        if (o < 16) ovList[o] = tid;
    }
    __syncthreads();

    // rare cooperative fallback: full exact scan for overflow rows
    const int nov = min(ovCnt, 16);
    for (int o = 0; o < nov; ++o) {
        const int rr = ovList[o];
        const float Az = znorm[rowBase + rr];
        const float4* zr4 = (const float4*)(z + ((size_t)(rowBase + rr) << 8));
        float bS = 3.4e38f; int bK = 0x7fffffff;
        for (int k = tid; k < K; k += 512) {
            const float4* ep4 = (const float4*)(emb + ((size_t)k << 8));
            float s = 0.f;
            #pragma unroll 8
            for (int d4 = 0; d4 < 64; ++d4) {
                float4 a = zr4[d4], b = ep4[d4];
                s = s + a.x * b.x; s = s + a.y * b.y;
                s = s + a.z * b.z; s = s + a.w * b.w;
            }
            float sc = (Az + enorm[k]) - 2.0f * s;
            if (sc < bS || (sc == bS && k < bK)) { bS = sc; bK = k; }
        }
        atomicMin(&sbits[rr], __float_as_uint(bS));
        __syncthreads();
        if (__float_as_uint(bS) == sbits[rr]) atomicMin(&sidx[rr], bK);
        __syncthreads();
    }

    // stage 2: first-index tie-break among exact-score minima
    if (bestK != 0x7fffffff && __float_as_uint(bestS) == sbits[r])
        atomicMin(&sidx[r], bestK);
    __syncthreads();
    if (tid < BM) idxf[rowBase + tid] = (float)sidx[tid];
}

// -------- kernel 3: gather z_q + loss accumulation --------
__global__ __launch_bounds__(256) void vq_gather(
    const float* __restrict__ z, const float* __restrict__ emb,
    const float* __restrict__ idxf, float* __restrict__ zq,
    float* __restrict__ loss, float scale) {
    const int tid = threadIdx.x;
    const int lane = tid & 63, w = tid >> 6;
    const int rowBase = blockIdx.x * 64;
    float lsum = 0.f;
    for (int t = 0; t < 16; ++t) {
        int gr = rowBase + w * 16 + t;
        int k = (int)idxf[gr];
        float4 e  = ((const float4*)emb)[(size_t)k * 64 + lane];
        float4 zv = ((const float4*)z)[(size_t)gr * 64 + lane];
        ((float4*)zq)[(size_t)gr * 64 + lane] = e;
        float dx = e.x - zv.x, dy = e.y - zv.y, dz = e.z - zv.z, dw = e.w - zv.w;
        lsum = fmaf(dx, dx, lsum); lsum = fmaf(dy, dy, lsum);
        lsum = fmaf(dz, dz, lsum); lsum = fmaf(dw, dw, lsum);
    }
    #pragma unroll
    for (int off = 32; off; off >>= 1) lsum += __shfl_down(lsum, off);
    __shared__ float ps[4];
    if (lane == 0) ps[w] = lsum;
    __syncthreads();
    if (tid == 0) atomicAdd(loss, (ps[0] + ps[1] + ps[2] + ps[3]) * scale);
}

extern "C" void kernel_launch(void* const* d_in, const int* in_sizes, int n_in,
                              void* d_out, int out_size, void* d_ws, size_t ws_size,
                              hipStream_t stream) {
    const float* z   = (const float*)d_in[0];
    const float* emb = (const float*)d_in[1];
    const int N = in_sizes[0] / D;   // 16384
    const int K = in_sizes[1] / D;   // 8192

    float* out  = (float*)d_out;
    float* zq   = out;
    const size_t Z = (size_t)N * D;  // 4,194,304 floats
    float* loss = out + Z;
    float* idxf = loss + 1;

    // scratch in the zq tail region (overwritten by gather at the end):
    char* base = (char*)zq;
    unsigned short* ebf = (unsigned short*)base;                         // 4 MB
    unsigned short* zb  = (unsigned short*)(base + (size_t)K * D * 2);   // 8 MB
    float* znorm = (float*)(base + (size_t)K * D * 2 + (size_t)N * D * 2);
    float* enorm = znorm + N;

    const int n4z = (N * D) / 4;
    vq_tobf16 <<<(n4z + 255) / 256, 256, 0, stream>>>(z, zb, n4z);
    vq_ebfrag <<<K / 64, 512, 0, stream>>>(emb, ebf);
    vq_rownorm<<<(N + 255) / 256, 256, 0, stream>>>(z, znorm, N, loss);
    vq_rownorm<<<(K + 255) / 256, 256, 0, stream>>>(emb, enorm, K, loss);
    vq_argmin_mfma<<<N / BM, 512, 0, stream>>>(z, emb, zb, ebf, znorm, enorm, idxf, K);
    vq_gather <<<N / 64, 256, 0, stream>>>(z, emb, idxf, zq, loss,
                                           1.25f / ((float)N * (float)D));
}

// Round 11
// 253.952 us; speedup vs baseline: 2.5248x; 1.0113x over previous
//
#include <hip/hip_runtime.h>
#include <hip/hip_bf16.h>

#define D 256
#define BM 32
#define NT 16       // code tiles: 16 x (8 waves x 64 codes) = 8192
#define CAP 128
#define MARGIN 1.2e-3f

typedef short bf16x8 __attribute__((ext_vector_type(8)));
typedef float f32x4 __attribute__((ext_vector_type(4)));

__device__ inline unsigned short f2bf(float f) {
    __hip_bfloat16 h = __float2bfloat16(f);
    return *reinterpret_cast<unsigned short*>(&h);
}

// -------- kernel 0a: fp32 -> bf16 convert (row-major, for z) --------
__global__ __launch_bounds__(256) void vq_tobf16(const float* __restrict__ in,
                                                 unsigned short* __restrict__ out, int n4) {
    int i = blockIdx.x * 256 + threadIdx.x;
    if (i >= n4) return;
    float4 v = ((const float4*)in)[i];
    ushort4 o;
    o.x = f2bf(v.x); o.y = f2bf(v.y); o.z = f2bf(v.z); o.w = f2bf(v.w);
    ((ushort4*)out)[i] = o;
}

// -------- kernel 0b: fp32 emb -> bf16 in MFMA-fragment order (R9-verified) ----
// fragment f(cb,kc,fc): lane l <- emb[cb*64 + fc*16 + (l&15)][kc*32 + (l>>4)*8 ..+7]
__global__ __launch_bounds__(512) void vq_ebfrag(const float* __restrict__ emb,
                                                 unsigned short* __restrict__ ebf) {
    const int cb = blockIdx.x;          // 0..127
    const int tid = threadIdx.x;
    const int kc = tid >> 6;            // wave index == kc 0..7
    const int l = tid & 63;
    const int q = l >> 4, lm = l & 15;
    const float4* emb4 = (const float4*)emb;
    #pragma unroll
    for (int fc = 0; fc < 4; ++fc) {
        const int code = cb * 64 + fc * 16 + lm;
        float4 a = emb4[(size_t)code * 64 + kc * 8 + q * 2];
        float4 b = emb4[(size_t)code * 64 + kc * 8 + q * 2 + 1];
        ushort4 o0, o1;
        o0.x = f2bf(a.x); o0.y = f2bf(a.y); o0.z = f2bf(a.z); o0.w = f2bf(a.w);
        o1.x = f2bf(b.x); o1.y = f2bf(b.y); o1.z = f2bf(b.z); o1.w = f2bf(b.w);
        unsigned short* dst = ebf + (((size_t)(cb * 8 + kc) * 4 + fc) << 9) + l * 8;
        *(ushort4*)dst = o0;
        *(ushort4*)(dst + 4) = o1;
    }
}

// -------- kernel 1: sequential fp32 row sum-of-squares (XLA elemental order) ----
__global__ __launch_bounds__(256) void vq_rownorm(const float* __restrict__ x,
                                                  float* __restrict__ out,
                                                  int rows, float* loss_zero) {
#pragma clang fp contract(off)
    int r = blockIdx.x * blockDim.x + threadIdx.x;
    if (r == 0 && loss_zero) loss_zero[0] = 0.f;
    if (r >= rows) return;
    const float* p = x + (size_t)r * D;
    float s = 0.f;
    for (int d = 0; d < D; ++d) {
        float v = p[d];
        float pr = v * v;
        s = s + pr;
    }
    out[r] = s;
}

// -------- kernel 2: single-pass MFMA filter (dbuf B prefetch) + exact rescore --
__global__ __launch_bounds__(512, 4) void vq_argmin_mfma(
    const float* __restrict__ z, const float* __restrict__ emb,
    const unsigned short* __restrict__ zb, const unsigned short* __restrict__ ebf,
    const float* __restrict__ znorm, const float* __restrict__ enorm,
    float* __restrict__ idxf, int K) {
#pragma clang fp contract(off)
    __shared__ unsigned short zsh[BM][264];   // 16,896 B
    __shared__ unsigned rowmin[BM];
    __shared__ int cnt[BM];
    __shared__ int candT[CAP][BM];            // 16,384 B (slot-major)
    __shared__ unsigned sbits[BM];
    __shared__ int sidx[BM];
    __shared__ int ovList[16];
    __shared__ int ovCnt;

    const int tid = threadIdx.x;
    const int w = tid >> 6;        // wave 0..7 (code-column)
    const int l = tid & 63;
    const int q = l >> 4;          // 0..3
    const int lm = l & 15;
    const int rowBase = blockIdx.x * BM;

    if (tid < BM) {
        rowmin[tid] = 0x7f800000u; cnt[tid] = 0;
        sbits[tid] = 0xffffffffu;  sidx[tid] = 0x7fffffff;
    }
    if (tid == 0) ovCnt = 0;

    // stage z tile (bf16) into padded LDS: 32 rows x 32 octets = 2 rounds
    #pragma unroll
    for (int rc = 0; rc < 2; ++rc) {
        int idx8 = tid + rc * 512;
        int row = idx8 >> 5, c8 = idx8 & 31;
        uint4 v = *(const uint4*)(zb + (((size_t)(rowBase + row)) << 8) + c8 * 8);
        *(uint4*)&zsh[row][c8 * 8] = v;
    }

    f32x4 nz4[2];
    #pragma unroll
    for (int fr = 0; fr < 2; ++fr)
        nz4[fr] = *(const f32x4*)&znorm[rowBase + fr * 16 + q * 4];

    __syncthreads();

    // double-buffered B fragments: bfr0 = even kc, bfr1 = odd kc (static regs)
    bf16x8 bfr0[4], bfr1[4];
    {   // prologue: tile 0, kc 0  (wave w's fragment base: cb = w)
        const unsigned short* fb0 = ebf + (((size_t)w) << 14) + l * 8;
        #pragma unroll
        for (int fc = 0; fc < 4; ++fc)
            bfr0[fc] = *(const bf16x8*)(fb0 + (fc << 9));
    }

    for (int tile = 0; tile < NT; ++tile) {
        const int cb = tile * 8 + w;                 // this wave's 64-code block
        const int codeBase = cb * 64;
        const unsigned short* fb = ebf + (((size_t)cb) << 14) + l * 8;
        float ne[4];
        #pragma unroll
        for (int fc = 0; fc < 4; ++fc) ne[fc] = enorm[codeBase + fc * 16 + lm];

        f32x4 acc[2][4];
        #pragma unroll
        for (int a = 0; a < 2; ++a)
            #pragma unroll
            for (int b = 0; b < 4; ++b) acc[a][b] = (f32x4)0.f;

        #pragma unroll
        for (int kc = 0; kc < 8; ++kc) {             // fully unrolled, static bufs
            bf16x8* curB = (kc & 1) ? bfr1 : bfr0;
            bf16x8* nxtB = (kc & 1) ? bfr0 : bfr1;
            if (kc < 7) {                            // prefetch kc+1, same tile
                #pragma unroll
                for (int fc = 0; fc < 4; ++fc)
                    nxtB[fc] = *(const bf16x8*)(fb + ((((kc + 1) << 2) + fc) << 9));
            } else if (tile + 1 < NT) {              // prefetch next tile's kc 0
                const unsigned short* fb2 = fb + (8u << 14);
                #pragma unroll
                for (int fc = 0; fc < 4; ++fc)
                    bfr0[fc] = *(const bf16x8*)(fb2 + (fc << 9));
            }

            bf16x8 af[2];
            #pragma unroll
            for (int fr = 0; fr < 2; ++fr)
                af[fr] = *(const bf16x8*)&zsh[fr * 16 + lm][kc * 32 + q * 8];
            #pragma unroll
            for (int fr = 0; fr < 2; ++fr)
                #pragma unroll
                for (int fc = 0; fc < 4; ++fc)
                    acc[fr][fc] = __builtin_amdgcn_mfma_f32_16x16x32_bf16(af[fr], curB[fc], acc[fr][fc], 0, 0, 0);
        }

        // ---- tile epilogue (no barriers): reg-min -> atomicMin -> collect ----
        f32x4 m4[2];
        #pragma unroll
        for (int fr = 0; fr < 2; ++fr) {
            #pragma unroll
            for (int e = 0; e < 4; ++e) {
                float m = 3.4e38f;
                #pragma unroll
                for (int fc = 0; fc < 4; ++fc) {
                    float s = (nz4[fr][e] + ne[fc]) - 2.0f * acc[fr][fc][e];
                    m = fminf(m, s);
                }
                m4[fr][e] = m;
                #pragma unroll
                for (int off = 1; off < 16; off <<= 1)
                    m = fminf(m, __shfl_xor(m, off));
                if (lm == 0)
                    atomicMin(&rowmin[fr * 16 + q * 4 + e], __float_as_uint(m));
            }
        }
        // threshold read (running rowmin >= finalMin, so capture guarantee holds)
        #pragma unroll
        for (int fr = 0; fr < 2; ++fr) {
            uint4 u = *(const uint4*)&rowmin[fr * 16 + q * 4];
            f32x4 thr = {__uint_as_float(u.x) + MARGIN, __uint_as_float(u.y) + MARGIN,
                         __uint_as_float(u.z) + MARGIN, __uint_as_float(u.w) + MARGIN};
            #pragma unroll
            for (int e = 0; e < 4; ++e) {
                if (m4[fr][e] >= thr[e]) continue;   // fast skip
                int row = fr * 16 + q * 4 + e;
                #pragma unroll
                for (int fc = 0; fc < 4; ++fc) {
                    float s = (nz4[fr][e] + ne[fc]) - 2.0f * acc[fr][fc][e];
                    if (s < thr[e]) {
                        int slot = atomicAdd(&cnt[row], 1);
                        if (slot < CAP) candT[slot][row] = codeBase + fc * 16 + lm;
                    }
                }
            }
        }
    }
    __syncthreads();

    // ================= exact rescore (bit-exact R2 semantics) ===================
    const int r = tid & 31;        // one row per lane-half
    const int c0 = tid >> 5;       // candidate slot, stride 16
    const int grow = rowBase + r;
    const float Anz = znorm[grow];
    const float4* zp4 = (const float4*)(z + ((size_t)grow << 8));

    float bestS = 3.4e38f; int bestK = 0x7fffffff;
    {
        const int n = min(cnt[r], CAP);
        for (int c = c0; c < n; c += 16) {
            int k = candT[c][r];
            const float4* ep4 = (const float4*)(emb + ((size_t)k << 8));
            float s = 0.f;
            #pragma unroll 8
            for (int d4 = 0; d4 < 64; ++d4) {
                float4 a = zp4[d4], b = ep4[d4];
                s = s + a.x * b.x;   // strict mul-then-add, ascending d
                s = s + a.y * b.y;
                s = s + a.z * b.z;
                s = s + a.w * b.w;
            }
            float sc = (Anz + enorm[k]) - 2.0f * s;
            if (sc < bestS || (sc == bestS && k < bestK)) { bestS = sc; bestK = k; }
        }
    }
    if (bestK != 0x7fffffff) atomicMin(&sbits[r], __float_as_uint(bestS));
    if (tid < BM && cnt[tid] > CAP) {          // overflow rows (should be never)
        int o = atomicAdd(&ovCnt, 1);
        if (o < 16) ovList[o] = tid;
    }
    __syncthreads();

    // rare cooperative fallback: full exact scan for overflow rows
    const int nov = min(ovCnt, 16);
    for (int o = 0; o < nov; ++o) {
        const int rr = ovList[o];
        const float Az = znorm[rowBase + rr];
        const float4* zr4 = (const float4*)(z + ((size_t)(rowBase + rr) << 8));
        float bS = 3.4e38f; int bK = 0x7fffffff;
        for (int k = tid; k < K; k += 512) {
            const float4* ep4 = (const float4*)(emb + ((size_t)k << 8));
            float s = 0.f;
            #pragma unroll 8
            for (int d4 = 0; d4 < 64; ++d4) {
                float4 a = zr4[d4], b = ep4[d4];
                s = s + a.x * b.x; s = s + a.y * b.y;
                s = s + a.z * b.z; s = s + a.w * b.w;
            }
            float sc = (Az + enorm[k]) - 2.0f * s;
            if (sc < bS || (sc == bS && k < bK)) { bS = sc; bK = k; }
        }
        atomicMin(&sbits[rr], __float_as_uint(bS));
        __syncthreads();
        if (__float_as_uint(bS) == sbits[rr]) atomicMin(&sidx[rr], bK);
        __syncthreads();
    }

    // stage 2: first-index tie-break among exact-score minima
    if (bestK != 0x7fffffff && __float_as_uint(bestS) == sbits[r])
        atomicMin(&sidx[r], bestK);
    __syncthreads();
    if (tid < BM) idxf[rowBase + tid] = (float)sidx[tid];
}

// -------- kernel 3: gather z_q + loss accumulation --------
__global__ __launch_bounds__(256) void vq_gather(
    const float* __restrict__ z, const float* __restrict__ emb,
    const float* __restrict__ idxf, float* __restrict__ zq,
    float* __restrict__ loss, float scale) {
    const int tid = threadIdx.x;
    const int lane = tid & 63, w = tid >> 6;
    const int rowBase = blockIdx.x * 64;
    float lsum = 0.f;
    for (int t = 0; t < 16; ++t) {
        int gr = rowBase + w * 16 + t;
        int k = (int)idxf[gr];
        float4 e  = ((const float4*)emb)[(size_t)k * 64 + lane];
        float4 zv = ((const float4*)z)[(size_t)gr * 64 + lane];
        ((float4*)zq)[(size_t)gr * 64 + lane] = e;
        float dx = e.x - zv.x, dy = e.y - zv.y, dz = e.z - zv.z, dw = e.w - zv.w;
        lsum = fmaf(dx, dx, lsum); lsum = fmaf(dy, dy, lsum);
        lsum = fmaf(dz, dz, lsum); lsum = fmaf(dw, dw, lsum);
    }
    #pragma unroll
    for (int off = 32; off; off >>= 1) lsum += __shfl_down(lsum, off);
    __shared__ float ps[4];
    if (lane == 0) ps[w] = lsum;
    __syncthreads();
    if (tid == 0) atomicAdd(loss, (ps[0] + ps[1] + ps[2] + ps[3]) * scale);
}

extern "C" void kernel_launch(void* const* d_in, const int* in_sizes, int n_in,
                              void* d_out, int out_size, void* d_ws, size_t ws_size,
                              hipStream_t stream) {
    const float* z   = (const float*)d_in[0];
    const float* emb = (const float*)d_in[1];
    const int N = in_sizes[0] / D;   // 16384
    const int K = in_sizes[1] / D;   // 8192

    float* out  = (float*)d_out;
    float* zq   = out;
    const size_t Z = (size_t)N * D;  // 4,194,304 floats
    float* loss = out + Z;
    float* idxf = loss + 1;

    // scratch in the zq tail region (overwritten by gather at the end):
    char* base = (char*)zq;
    unsigned short* ebf = (unsigned short*)base;                         // 4 MB
    unsigned short* zb  = (unsigned short*)(base + (size_t)K * D * 2);   // 8 MB
    float* znorm = (float*)(base + (size_t)K * D * 2 + (size_t)N * D * 2);
    float* enorm = znorm + N;

    const int n4z = (N * D) / 4;
    vq_tobf16 <<<(n4z + 255) / 256, 256, 0, stream>>>(z, zb, n4z);
    vq_ebfrag <<<K / 64, 512, 0, stream>>>(emb, ebf);
    vq_rownorm<<<(N + 255) / 256, 256, 0, stream>>>(z, znorm, N, loss);
    vq_rownorm<<<(K + 255) / 256, 256, 0, stream>>>(emb, enorm, K, loss);
    vq_argmin_mfma<<<N / BM, 512, 0, stream>>>(z, emb, zb, ebf, znorm, enorm, idxf, K);
    vq_gather <<<N / 64, 256, 0, stream>>>(z, emb, idxf, zq, loss,
                                           1.25f / ((float)N * (float)D));
}